// Round 1
// baseline (1659.096 us; speedup 1.0000x reference)
//
#include <hip/hip_runtime.h>

#define N_NODES 50000
#define D 128
#define N_EDGES 400000

// Fused projection GEMM: computes op(X) @ W for W in {Wk,Wq,Wv,Ws} selected by
// blockIdx.y. sel==3 additionally adds bias (the skip path x@Ws + b) and writes
// to Agg, which the edge kernel then atomically accumulates into.
// op = relu iff RELU_IN (layer-2 input is relu(agg1); h has no other consumer).
// Tile: 128(M) x 128(N), K staged in chunks of 32. 256 threads, 8x8 microtile.
template<bool RELU_IN>
__global__ __launch_bounds__(256)
void kqvs_gemm(const float* __restrict__ X,
               const float* __restrict__ Wk, const float* __restrict__ Wq,
               const float* __restrict__ Wv, const float* __restrict__ Ws,
               const float* __restrict__ bias,
               float* __restrict__ Kb, float* __restrict__ Qb,
               float* __restrict__ Vb, float* __restrict__ Agg)
{
    // As pad-1: inner-loop scalar reads As[m][k] broadcast across tx -> conflict-free.
    // Bs pad-4: keeps 16B alignment for float4 reads; 2-way bank aliasing is free.
    __shared__ float As[128][33];
    __shared__ float Bs[32][132];

    const int m0  = blockIdx.x * 128;
    const int sel = blockIdx.y;
    const float* __restrict__ W   = (sel == 0) ? Wk : (sel == 1) ? Wq : (sel == 2) ? Wv : Ws;
    float*       __restrict__ Out = (sel == 0) ? Kb : (sel == 1) ? Qb : (sel == 2) ? Vb : Agg;

    const int tid = threadIdx.x;
    const int tx  = tid & 15;   // N direction, 8 cols each
    const int ty  = tid >> 4;   // M direction, 8 rows each

    float acc[8][8];
#pragma unroll
    for (int i = 0; i < 8; ++i)
#pragma unroll
        for (int j = 0; j < 8; ++j) acc[i][j] = 0.f;

    for (int kc = 0; kc < D; kc += 32) {
        // Stage A tile: 128 rows x 32 k. 1024 float4, 4 per thread, coalesced.
#pragma unroll
        for (int i = 0; i < 4; ++i) {
            int idx = tid + 256 * i;      // 0..1023
            int r   = idx >> 3;           // 0..127
            int c4  = idx & 7;            // 0..7
            int row = m0 + r;
            float4 a = make_float4(0.f, 0.f, 0.f, 0.f);
            if (row < N_NODES) {
                a = *(const float4*)(X + (size_t)row * D + kc + c4 * 4);
                if (RELU_IN) {
                    a.x = fmaxf(a.x, 0.f); a.y = fmaxf(a.y, 0.f);
                    a.z = fmaxf(a.z, 0.f); a.w = fmaxf(a.w, 0.f);
                }
            }
            int c = c4 * 4;
            As[r][c + 0] = a.x; As[r][c + 1] = a.y;
            As[r][c + 2] = a.z; As[r][c + 3] = a.w;
        }
        // Stage B tile: 32 k x 128 cols. float4 writes, conflict-free.
#pragma unroll
        for (int i = 0; i < 4; ++i) {
            int idx = tid + 256 * i;      // 0..1023
            int k   = idx >> 5;           // 0..31
            int c4  = idx & 31;           // 0..31
            float4 b = *(const float4*)(W + (size_t)(kc + k) * D + c4 * 4);
            *(float4*)&Bs[k][c4 * 4] = b;
        }
        __syncthreads();

#pragma unroll
        for (int k = 0; k < 32; ++k) {
            float a[8], b[8];
#pragma unroll
            for (int i = 0; i < 8; ++i) a[i] = As[ty * 8 + i][k];
            float4 b0 = *(const float4*)&Bs[k][tx * 8];
            float4 b1 = *(const float4*)&Bs[k][tx * 8 + 4];
            b[0] = b0.x; b[1] = b0.y; b[2] = b0.z; b[3] = b0.w;
            b[4] = b1.x; b[5] = b1.y; b[6] = b1.z; b[7] = b1.w;
#pragma unroll
            for (int i = 0; i < 8; ++i)
#pragma unroll
                for (int j = 0; j < 8; ++j)
                    acc[i][j] = fmaf(a[i], b[j], acc[i][j]);
        }
        __syncthreads();
    }

    // Epilogue: float4 stores; bias only on the skip/agg path.
#pragma unroll
    for (int i = 0; i < 8; ++i) {
        int row = m0 + ty * 8 + i;
        if (row >= N_NODES) continue;
#pragma unroll
        for (int jh = 0; jh < 2; ++jh) {
            int c = tx * 8 + jh * 4;
            float4 o;
            o.x = acc[i][jh * 4 + 0]; o.y = acc[i][jh * 4 + 1];
            o.z = acc[i][jh * 4 + 2]; o.w = acc[i][jh * 4 + 3];
            if (sel == 3) {
                o.x += bias[c + 0]; o.y += bias[c + 1];
                o.z += bias[c + 2]; o.w += bias[c + 3];
            }
            *(float4*)(Out + (size_t)row * D + c) = o;
        }
    }
}

// Edge phase: eta = sigmoid(k[tgt] + q[src]); msg = eta * v[src];
// atomic scatter-add into Agg[tgt]. 32 threads per edge, float4 per thread.
__global__ __launch_bounds__(256)
void edge_msg(const int* __restrict__ src, const int* __restrict__ tgt,
              const float* __restrict__ K, const float* __restrict__ Q,
              const float* __restrict__ V, float* __restrict__ Agg)
{
    int tid = blockIdx.x * 256 + threadIdx.x;
    int e   = tid >> 5;        // edge index
    int c   = tid & 31;        // float4 index within the 128-dim row
    if (e >= N_EDGES) return;
    int s = src[e];
    int t = tgt[e];

    const float4 k4 = ((const float4*)K)[(size_t)t * 32 + c];
    const float4 q4 = ((const float4*)Q)[(size_t)s * 32 + c];
    const float4 v4 = ((const float4*)V)[(size_t)s * 32 + c];

    float4 m;
    m.x = v4.x / (1.f + __expf(-(k4.x + q4.x)));
    m.y = v4.y / (1.f + __expf(-(k4.y + q4.y)));
    m.z = v4.z / (1.f + __expf(-(k4.z + q4.z)));
    m.w = v4.w / (1.f + __expf(-(k4.w + q4.w)));

    float* dst = Agg + (size_t)t * D + c * 4;
    atomicAdd(dst + 0, m.x);
    atomicAdd(dst + 1, m.y);
    atomicAdd(dst + 2, m.z);
    atomicAdd(dst + 3, m.w);
}

extern "C" void kernel_launch(void* const* d_in, const int* in_sizes, int n_in,
                              void* d_out, int out_size, void* d_ws, size_t ws_size,
                              hipStream_t stream)
{
    const float* x   = (const float*)d_in[0];
    const int*   ei  = (const int*)d_in[1];
    const float* Wk1 = (const float*)d_in[2];
    const float* Wq1 = (const float*)d_in[3];
    const float* Wv1 = (const float*)d_in[4];
    const float* Ws1 = (const float*)d_in[5];
    const float* b1  = (const float*)d_in[6];
    const float* Wk2 = (const float*)d_in[7];
    const float* Wq2 = (const float*)d_in[8];
    const float* Wv2 = (const float*)d_in[9];
    const float* Ws2 = (const float*)d_in[10];
    const float* b2  = (const float*)d_in[11];

    const int* src = ei;             // edge_index[0]
    const int* tgt = ei + N_EDGES;   // edge_index[1]

    const size_t nd = (size_t)N_NODES * D;
    float* kb  = (float*)d_ws;
    float* qb  = kb + nd;
    float* vb  = qb + nd;
    float* h   = vb + nd;            // layer-1 aggregate (pre-relu)
    float* out = (float*)d_out;

    dim3 gemm_grid((N_NODES + 127) / 128, 4);
    const int edge_blocks = (N_EDGES * 32) / 256;   // 50000

    // Layer 1: agg1 initialized by the s-projection (x@Ws1 + b1), edges add in.
    kqvs_gemm<false><<<gemm_grid, 256, 0, stream>>>(x, Wk1, Wq1, Wv1, Ws1, b1,
                                                    kb, qb, vb, h);
    edge_msg<<<edge_blocks, 256, 0, stream>>>(src, tgt, kb, qb, vb, h);

    // Layer 2: relu fused into GEMM input load; agg2 target is d_out directly.
    kqvs_gemm<true><<<gemm_grid, 256, 0, stream>>>(h, Wk2, Wq2, Wv2, Ws2, b2,
                                                   kb, qb, vb, out);
    edge_msg<<<edge_blocks, 256, 0, stream>>>(src, tgt, kb, qb, vb, out);
}

// Round 2
// 486.767 us; speedup vs baseline: 3.4084x; 3.4084x over previous
//
#include <hip/hip_runtime.h>

#define N_NODES 50000
#define D 128
#define N_EDGES 400000
#define NCHUNKS ((N_NODES + 255) / 256)   // 196

// ---------------------------------------------------------------------------
// Fused projection GEMM (unchanged from R0): op(X) @ {Wk,Wq,Wv,Ws} by blockIdx.y.
// sel==3 adds bias (skip path x@Ws + b) -> Agg; node_agg accumulates into it.
// ---------------------------------------------------------------------------
template<bool RELU_IN>
__global__ __launch_bounds__(256)
void kqvs_gemm(const float* __restrict__ X,
               const float* __restrict__ Wk, const float* __restrict__ Wq,
               const float* __restrict__ Wv, const float* __restrict__ Ws,
               const float* __restrict__ bias,
               float* __restrict__ Kb, float* __restrict__ Qb,
               float* __restrict__ Vb, float* __restrict__ Agg)
{
    __shared__ float As[128][33];
    __shared__ float Bs[32][132];

    const int m0  = blockIdx.x * 128;
    const int sel = blockIdx.y;
    const float* __restrict__ W   = (sel == 0) ? Wk : (sel == 1) ? Wq : (sel == 2) ? Wv : Ws;
    float*       __restrict__ Out = (sel == 0) ? Kb : (sel == 1) ? Qb : (sel == 2) ? Vb : Agg;

    const int tid = threadIdx.x;
    const int tx  = tid & 15;
    const int ty  = tid >> 4;

    float acc[8][8];
#pragma unroll
    for (int i = 0; i < 8; ++i)
#pragma unroll
        for (int j = 0; j < 8; ++j) acc[i][j] = 0.f;

    for (int kc = 0; kc < D; kc += 32) {
#pragma unroll
        for (int i = 0; i < 4; ++i) {
            int idx = tid + 256 * i;
            int r   = idx >> 3;
            int c4  = idx & 7;
            int row = m0 + r;
            float4 a = make_float4(0.f, 0.f, 0.f, 0.f);
            if (row < N_NODES) {
                a = *(const float4*)(X + (size_t)row * D + kc + c4 * 4);
                if (RELU_IN) {
                    a.x = fmaxf(a.x, 0.f); a.y = fmaxf(a.y, 0.f);
                    a.z = fmaxf(a.z, 0.f); a.w = fmaxf(a.w, 0.f);
                }
            }
            int c = c4 * 4;
            As[r][c + 0] = a.x; As[r][c + 1] = a.y;
            As[r][c + 2] = a.z; As[r][c + 3] = a.w;
        }
#pragma unroll
        for (int i = 0; i < 4; ++i) {
            int idx = tid + 256 * i;
            int k   = idx >> 5;
            int c4  = idx & 31;
            float4 b = *(const float4*)(W + (size_t)(kc + k) * D + c4 * 4);
            *(float4*)&Bs[k][c4 * 4] = b;
        }
        __syncthreads();

#pragma unroll
        for (int k = 0; k < 32; ++k) {
            float a[8], b[8];
#pragma unroll
            for (int i = 0; i < 8; ++i) a[i] = As[ty * 8 + i][k];
            float4 b0 = *(const float4*)&Bs[k][tx * 8];
            float4 b1 = *(const float4*)&Bs[k][tx * 8 + 4];
            b[0] = b0.x; b[1] = b0.y; b[2] = b0.z; b[3] = b0.w;
            b[4] = b1.x; b[5] = b1.y; b[6] = b1.z; b[7] = b1.w;
#pragma unroll
            for (int i = 0; i < 8; ++i)
#pragma unroll
                for (int j = 0; j < 8; ++j)
                    acc[i][j] = fmaf(a[i], b[j], acc[i][j]);
        }
        __syncthreads();
    }

#pragma unroll
    for (int i = 0; i < 8; ++i) {
        int row = m0 + ty * 8 + i;
        if (row >= N_NODES) continue;
#pragma unroll
        for (int jh = 0; jh < 2; ++jh) {
            int c = tx * 8 + jh * 4;
            float4 o;
            o.x = acc[i][jh * 4 + 0]; o.y = acc[i][jh * 4 + 1];
            o.z = acc[i][jh * 4 + 2]; o.w = acc[i][jh * 4 + 3];
            if (sel == 3) {
                o.x += bias[c + 0]; o.y += bias[c + 1];
                o.z += bias[c + 2]; o.w += bias[c + 3];
            }
            *(float4*)(Out + (size_t)row * D + c) = o;
        }
    }
}

// ---------------------------------------------------------------------------
// CSR build (counting sort by target), done once per launch, reused both layers.
// ---------------------------------------------------------------------------
__global__ __launch_bounds__(256)
void hist_kernel(const int* __restrict__ tgt, int* __restrict__ counts)
{
    int e = blockIdx.x * 256 + threadIdx.x;
    if (e < N_EDGES) atomicAdd(&counts[tgt[e]], 1);
}

__global__ __launch_bounds__(256)
void chunk_reduce(const int* __restrict__ counts, int* __restrict__ chunk_sum)
{
    __shared__ int s[256];
    int i = blockIdx.x * 256 + threadIdx.x;
    s[threadIdx.x] = (i < N_NODES) ? counts[i] : 0;
    __syncthreads();
    for (int d = 128; d > 0; d >>= 1) {
        if (threadIdx.x < d) s[threadIdx.x] += s[threadIdx.x + d];
        __syncthreads();
    }
    if (threadIdx.x == 0) chunk_sum[blockIdx.x] = s[0];
}

__global__ void scan_sums(const int* __restrict__ chunk_sum,
                          int* __restrict__ chunk_off, int* __restrict__ off)
{
    if (threadIdx.x == 0) {
        int run = 0;
        for (int i = 0; i < NCHUNKS; ++i) { chunk_off[i] = run; run += chunk_sum[i]; }
        off[N_NODES] = run;   // == N_EDGES
    }
}

__global__ __launch_bounds__(256)
void scan_chunks(const int* __restrict__ counts, const int* __restrict__ chunk_off,
                 int* __restrict__ off, int* __restrict__ cursor)
{
    __shared__ int s[256];
    int i = blockIdx.x * 256 + threadIdx.x;
    int v = (i < N_NODES) ? counts[i] : 0;
    s[threadIdx.x] = v;
    __syncthreads();
    // Hillis-Steele inclusive scan
    for (int d = 1; d < 256; d <<= 1) {
        int t = (threadIdx.x >= d) ? s[threadIdx.x - d] : 0;
        __syncthreads();
        s[threadIdx.x] += t;
        __syncthreads();
    }
    if (i < N_NODES) {
        int excl = s[threadIdx.x] - v + chunk_off[blockIdx.x];
        off[i]    = excl;
        cursor[i] = excl;
    }
}

__global__ __launch_bounds__(256)
void scatter_kernel(const int* __restrict__ src, const int* __restrict__ tgt,
                    int* __restrict__ cursor, int* __restrict__ es)
{
    int e = blockIdx.x * 256 + threadIdx.x;
    if (e < N_EDGES) {
        int pos = atomicAdd(&cursor[tgt[e]], 1);
        es[pos] = src[e];
    }
}

// ---------------------------------------------------------------------------
// Per-node aggregation, atomic-free. One wave (64 lanes) per target node,
// 4 nodes per 256-thread block. Lane owns 2 consecutive floats (float2).
// Agg already holds x@Ws + b from the GEMM; we add the gated messages.
// ---------------------------------------------------------------------------
__global__ __launch_bounds__(256)
void node_agg(const int* __restrict__ off, const int* __restrict__ es,
              const float* __restrict__ K, const float* __restrict__ Q,
              const float* __restrict__ V, float* __restrict__ Agg)
{
    const int warp = threadIdx.x >> 6;
    const int lane = threadIdx.x & 63;
    const int t    = blockIdx.x * 4 + warp;   // grid is exactly N_NODES/4

    const float2* __restrict__ K2 = (const float2*)K;
    const float2* __restrict__ Q2 = (const float2*)Q;
    const float2* __restrict__ V2 = (const float2*)V;

    const float2 k2 = K2[(size_t)t * 64 + lane];
    float2 acc = make_float2(0.f, 0.f);

    const int e1 = off[t + 1];
    for (int e = off[t]; e < e1; ++e) {
        int s = es[e];                     // wave-uniform -> scalar load
        float2 q2 = Q2[(size_t)s * 64 + lane];
        float2 v2 = V2[(size_t)s * 64 + lane];
        acc.x += v2.x / (1.f + __expf(-(k2.x + q2.x)));
        acc.y += v2.y / (1.f + __expf(-(k2.y + q2.y)));
    }

    float2* A2 = (float2*)Agg;
    float2 a = A2[(size_t)t * 64 + lane];
    a.x += acc.x; a.y += acc.y;
    A2[(size_t)t * 64 + lane] = a;
}

extern "C" void kernel_launch(void* const* d_in, const int* in_sizes, int n_in,
                              void* d_out, int out_size, void* d_ws, size_t ws_size,
                              hipStream_t stream)
{
    const float* x   = (const float*)d_in[0];
    const int*   ei  = (const int*)d_in[1];
    const float* Wk1 = (const float*)d_in[2];
    const float* Wq1 = (const float*)d_in[3];
    const float* Wv1 = (const float*)d_in[4];
    const float* Ws1 = (const float*)d_in[5];
    const float* b1  = (const float*)d_in[6];
    const float* Wk2 = (const float*)d_in[7];
    const float* Wq2 = (const float*)d_in[8];
    const float* Wv2 = (const float*)d_in[9];
    const float* Ws2 = (const float*)d_in[10];
    const float* b2  = (const float*)d_in[11];

    const int* src = ei;
    const int* tgt = ei + N_EDGES;

    const size_t nd = (size_t)N_NODES * D;
    float* kb  = (float*)d_ws;
    float* qb  = kb + nd;
    float* vb  = qb + nd;
    float* h   = vb + nd;
    int*   counts    = (int*)(h + nd);
    int*   off       = counts + N_NODES;          // N_NODES + 1
    int*   cursor    = off + N_NODES + 1;
    int*   es        = cursor + N_NODES;
    int*   chunk_sum = es + N_EDGES;              // NCHUNKS
    int*   chunk_off = chunk_sum + NCHUNKS;
    float* out = (float*)d_out;

    dim3 gemm_grid((N_NODES + 127) / 128, 4);
    const int eb = (N_EDGES + 255) / 256;

    // --- Build CSR (by target) once; reused by both layers ---
    hipMemsetAsync(counts, 0, N_NODES * sizeof(int), stream);
    hist_kernel   <<<eb, 256, 0, stream>>>(tgt, counts);
    chunk_reduce  <<<NCHUNKS, 256, 0, stream>>>(counts, chunk_sum);
    scan_sums     <<<1, 64, 0, stream>>>(chunk_sum, chunk_off, off);
    scan_chunks   <<<NCHUNKS, 256, 0, stream>>>(counts, chunk_off, off, cursor);
    scatter_kernel<<<eb, 256, 0, stream>>>(src, tgt, cursor, es);

    // --- Layer 1 ---
    kqvs_gemm<false><<<gemm_grid, 256, 0, stream>>>(x, Wk1, Wq1, Wv1, Ws1, b1,
                                                    kb, qb, vb, h);
    node_agg<<<N_NODES / 4, 256, 0, stream>>>(off, es, kb, qb, vb, h);

    // --- Layer 2 (relu fused into GEMM input load) ---
    kqvs_gemm<true><<<gemm_grid, 256, 0, stream>>>(h, Wk2, Wq2, Wv2, Ws2, b2,
                                                   kb, qb, vb, out);
    node_agg<<<N_NODES / 4, 256, 0, stream>>>(off, es, kb, qb, vb, out);
}

// Round 3
// 347.029 us; speedup vs baseline: 4.7809x; 1.4027x over previous
//
#include <hip/hip_runtime.h>

#define N_NODES 50000
#define D 128
#define N_EDGES 400000
#define NCHUNKS ((N_NODES + 255) / 256)   // 196
#define NBLK ((N_NODES + 127) / 128)      // 391
#define W_FRAG_SHORTS 16384               // 32 frags * 64 lanes * 8 bf16 per weight matrix

typedef short s8v  __attribute__((ext_vector_type(8)));   // 8 bf16 (4 VGPRs)
typedef float f4v  __attribute__((ext_vector_type(4)));   // MFMA accumulator

// float -> bf16 round-to-nearest-even (branchless; inputs are normal floats)
__device__ __forceinline__ unsigned short f2bf(float f) {
    unsigned int u = __float_as_uint(f);
    u += 0x7FFFu + ((u >> 16) & 1u);
    return (unsigned short)(u >> 16);
}
__device__ __forceinline__ float bflo(unsigned int u) { return __uint_as_float(u << 16); }
__device__ __forceinline__ float bfhi(unsigned int u) { return __uint_as_float(u & 0xFFFF0000u); }

// ---------------------------------------------------------------------------
// Weight prep: fp32 W[k][n] (128x128) -> bf16 B-fragment-major Wt.
// Fragment layout for mfma_f32_16x16x32_bf16 B operand: frag = n_tile*4 + kc,
// lane = (n%16) + 16*quad, 8 consecutive k (k = kc*32 + quad*8 + j).
// GEMM then loads B as coalesced 16B/lane straight from global (L2-resident).
// ---------------------------------------------------------------------------
__global__ __launch_bounds__(256)
void make_wt(const float* __restrict__ W0, const float* __restrict__ W1,
             const float* __restrict__ W2, const float* __restrict__ W3,
             const float* __restrict__ W4, const float* __restrict__ W5,
             const float* __restrict__ W6, const float* __restrict__ W7,
             short* __restrict__ Wt)
{
    const int wsel = blockIdx.x;     // 0..7
    const float* W = (wsel == 0) ? W0 : (wsel == 1) ? W1 : (wsel == 2) ? W2 :
                     (wsel == 3) ? W3 : (wsel == 4) ? W4 : (wsel == 5) ? W5 :
                     (wsel == 6) ? W6 : W7;
    const int slot = blockIdx.y * 256 + threadIdx.x;   // 0..2047
    const int frag = slot >> 6;
    const int lane = slot & 63;
    const int n    = (frag >> 2) * 16 + (lane & 15);
    const int kc   = frag & 3;
    const int quad = lane >> 4;
    const int k0   = kc * 32 + quad * 8;

    s8v v;
#pragma unroll
    for (int j = 0; j < 8; ++j)
        v[j] = (short)f2bf(W[(size_t)(k0 + j) * D + n]);
    *(s8v*)(Wt + (size_t)wsel * W_FRAG_SHORTS + (size_t)slot * 8) = v;
}

// ---------------------------------------------------------------------------
// bf16-MFMA projection GEMM. Block: 128x128 output tile for one of 4 weight
// matrices (blockIdx.y = sel). Full K=128 of the A tile staged ONCE into LDS
// in A-fragment-major bf16 (convert + optional relu fused; XOR swizzle keeps
// staging writes at 2-way bank aliasing = free). B frags come from global
// fragment-major Wt. sel<3 -> bf16 K/Q/V outputs; sel==3 -> fp32 Agg = X@Ws+b.
// ---------------------------------------------------------------------------
template<bool RELU_IN>
__global__ __launch_bounds__(256)
void gemm_mfma(const float* __restrict__ X, const short* __restrict__ WtL,
               const float* __restrict__ bias,
               short* __restrict__ Kb, short* __restrict__ Qb,
               short* __restrict__ Vb, float* __restrict__ Agg)
{
    __shared__ short As[16384];   // 32 frags * 512 shorts = 32 KB

    const int m0  = blockIdx.x * 128;
    const int sel = blockIdx.y;
    const int tid = threadIdx.x;

    // ---- Stage A tile (128 rows x 128 k) as fragment-major bf16 ----
#pragma unroll
    for (int i = 0; i < 8; ++i) {
        const int m   = (tid >> 4) + 16 * i;   // 0..127
        const int oct = tid & 15;              // 8-k group
        const int row = m0 + m;
        float4 a0 = make_float4(0.f, 0.f, 0.f, 0.f);
        float4 a1 = make_float4(0.f, 0.f, 0.f, 0.f);
        if (row < N_NODES) {
            const float* p = X + (size_t)row * D + oct * 8;
            a0 = *(const float4*)p;
            a1 = *(const float4*)(p + 4);
            if (RELU_IN) {
                a0.x = fmaxf(a0.x, 0.f); a0.y = fmaxf(a0.y, 0.f);
                a0.z = fmaxf(a0.z, 0.f); a0.w = fmaxf(a0.w, 0.f);
                a1.x = fmaxf(a1.x, 0.f); a1.y = fmaxf(a1.y, 0.f);
                a1.z = fmaxf(a1.z, 0.f); a1.w = fmaxf(a1.w, 0.f);
            }
        }
        const int kc   = oct >> 2;
        const int quad = oct & 3;
        const int frag = (m >> 4) * 4 + kc;
        const int slot = ((m & 15) + 16 * quad) ^ (kc << 1);
        s8v v;
        v[0] = (short)f2bf(a0.x); v[1] = (short)f2bf(a0.y);
        v[2] = (short)f2bf(a0.z); v[3] = (short)f2bf(a0.w);
        v[4] = (short)f2bf(a1.x); v[5] = (short)f2bf(a1.y);
        v[6] = (short)f2bf(a1.z); v[7] = (short)f2bf(a1.w);
        *(s8v*)&As[frag * 512 + slot * 8] = v;
    }
    __syncthreads();

    // ---- MFMA main: wave w covers rows 32w..32w+31, all 128 cols ----
    const int lane = tid & 63;
    const int w    = tid >> 6;
    const short* __restrict__ Wf = WtL + (size_t)sel * W_FRAG_SHORTS;

    f4v acc[2][8];
#pragma unroll
    for (int mt = 0; mt < 2; ++mt)
#pragma unroll
        for (int nt = 0; nt < 8; ++nt)
            acc[mt][nt] = (f4v){0.f, 0.f, 0.f, 0.f};

#pragma unroll
    for (int kc = 0; kc < 4; ++kc) {
        const int sl = (lane ^ (kc << 1)) * 8;
        s8v a0 = *(const s8v*)&As[((2 * w + 0) * 4 + kc) * 512 + sl];
        s8v a1 = *(const s8v*)&As[((2 * w + 1) * 4 + kc) * 512 + sl];
#pragma unroll
        for (int nt = 0; nt < 8; ++nt) {
            s8v b = *(const s8v*)(Wf + (size_t)(nt * 4 + kc) * 512 + lane * 8);
            acc[0][nt] = __builtin_amdgcn_mfma_f32_16x16x32_bf16(a0, b, acc[0][nt], 0, 0, 0);
            acc[1][nt] = __builtin_amdgcn_mfma_f32_16x16x32_bf16(a1, b, acc[1][nt], 0, 0, 0);
        }
    }

    // ---- Epilogue: C layout col=lane&15, row=(lane>>4)*4+reg ----
    const int col = lane & 15;
#pragma unroll
    for (int mt = 0; mt < 2; ++mt) {
        const int rbase = m0 + (2 * w + mt) * 16 + (lane >> 4) * 4;
        if (sel == 3) {
#pragma unroll
            for (int nt = 0; nt < 8; ++nt) {
                const float bv = bias[nt * 16 + col];
#pragma unroll
                for (int i = 0; i < 4; ++i) {
                    const int row = rbase + i;
                    if (row < N_NODES)
                        Agg[(size_t)row * D + nt * 16 + col] = acc[mt][nt][i] + bv;
                }
            }
        } else {
            short* __restrict__ Outb = (sel == 0) ? Kb : (sel == 1) ? Qb : Vb;
#pragma unroll
            for (int nt = 0; nt < 8; ++nt)
#pragma unroll
                for (int i = 0; i < 4; ++i) {
                    const int row = rbase + i;
                    if (row < N_NODES)
                        Outb[(size_t)row * D + nt * 16 + col] = (short)f2bf(acc[mt][nt][i]);
                }
        }
    }
}

// ---------------------------------------------------------------------------
// CSR build (counting sort by target) — unchanged from R1.
// ---------------------------------------------------------------------------
__global__ __launch_bounds__(256)
void hist_kernel(const int* __restrict__ tgt, int* __restrict__ counts)
{
    int e = blockIdx.x * 256 + threadIdx.x;
    if (e < N_EDGES) atomicAdd(&counts[tgt[e]], 1);
}

__global__ __launch_bounds__(256)
void chunk_reduce(const int* __restrict__ counts, int* __restrict__ chunk_sum)
{
    __shared__ int s[256];
    int i = blockIdx.x * 256 + threadIdx.x;
    s[threadIdx.x] = (i < N_NODES) ? counts[i] : 0;
    __syncthreads();
    for (int d = 128; d > 0; d >>= 1) {
        if (threadIdx.x < d) s[threadIdx.x] += s[threadIdx.x + d];
        __syncthreads();
    }
    if (threadIdx.x == 0) chunk_sum[blockIdx.x] = s[0];
}

__global__ void scan_sums(const int* __restrict__ chunk_sum,
                          int* __restrict__ chunk_off, int* __restrict__ off)
{
    if (threadIdx.x == 0) {
        int run = 0;
        for (int i = 0; i < NCHUNKS; ++i) { chunk_off[i] = run; run += chunk_sum[i]; }
        off[N_NODES] = run;
    }
}

__global__ __launch_bounds__(256)
void scan_chunks(const int* __restrict__ counts, const int* __restrict__ chunk_off,
                 int* __restrict__ off, int* __restrict__ cursor)
{
    __shared__ int s[256];
    int i = blockIdx.x * 256 + threadIdx.x;
    int v = (i < N_NODES) ? counts[i] : 0;
    s[threadIdx.x] = v;
    __syncthreads();
    for (int d = 1; d < 256; d <<= 1) {
        int t = (threadIdx.x >= d) ? s[threadIdx.x - d] : 0;
        __syncthreads();
        s[threadIdx.x] += t;
        __syncthreads();
    }
    if (i < N_NODES) {
        int excl = s[threadIdx.x] - v + chunk_off[blockIdx.x];
        off[i]    = excl;
        cursor[i] = excl;
    }
}

__global__ __launch_bounds__(256)
void scatter_kernel(const int* __restrict__ src, const int* __restrict__ tgt,
                    int* __restrict__ cursor, int* __restrict__ es)
{
    int e = blockIdx.x * 256 + threadIdx.x;
    if (e < N_EDGES) {
        int pos = atomicAdd(&cursor[tgt[e]], 1);
        es[pos] = src[e];
    }
}

// ---------------------------------------------------------------------------
// Atomic-free per-node aggregation over bf16 K/Q/V. One wave per target node,
// lane owns 2 dims (one packed uint). Agg already holds x@Ws+b (fp32).
// ---------------------------------------------------------------------------
__global__ __launch_bounds__(256)
void node_agg(const int* __restrict__ off, const int* __restrict__ es,
              const short* __restrict__ K, const short* __restrict__ Q,
              const short* __restrict__ V, float* __restrict__ Agg)
{
    const int warp = threadIdx.x >> 6;
    const int lane = threadIdx.x & 63;
    const int t    = blockIdx.x * 4 + warp;

    const unsigned int* __restrict__ K1 = (const unsigned int*)K;
    const unsigned int* __restrict__ Q1 = (const unsigned int*)Q;
    const unsigned int* __restrict__ V1 = (const unsigned int*)V;

    const unsigned int ku = K1[(size_t)t * 64 + lane];
    const float kx = bflo(ku), ky = bfhi(ku);
    float accx = 0.f, accy = 0.f;

    const int e1 = off[t + 1];
    for (int e = off[t]; e < e1; ++e) {
        const int s = es[e];
        const unsigned int qu = Q1[(size_t)s * 64 + lane];
        const unsigned int vu = V1[(size_t)s * 64 + lane];
        accx += bflo(vu) / (1.f + __expf(-(kx + bflo(qu))));
        accy += bfhi(vu) / (1.f + __expf(-(ky + bfhi(qu))));
    }

    float2* A2 = (float2*)Agg;
    float2 a = A2[(size_t)t * 64 + lane];
    a.x += accx; a.y += accy;
    A2[(size_t)t * 64 + lane] = a;
}

extern "C" void kernel_launch(void* const* d_in, const int* in_sizes, int n_in,
                              void* d_out, int out_size, void* d_ws, size_t ws_size,
                              hipStream_t stream)
{
    const float* x   = (const float*)d_in[0];
    const int*   ei  = (const int*)d_in[1];
    const float* Wk1 = (const float*)d_in[2];
    const float* Wq1 = (const float*)d_in[3];
    const float* Wv1 = (const float*)d_in[4];
    const float* Ws1 = (const float*)d_in[5];
    const float* b1  = (const float*)d_in[6];
    const float* Wk2 = (const float*)d_in[7];
    const float* Wq2 = (const float*)d_in[8];
    const float* Wv2 = (const float*)d_in[9];
    const float* Ws2 = (const float*)d_in[10];
    const float* b2  = (const float*)d_in[11];

    const int* src = ei;
    const int* tgt = ei + N_EDGES;

    const size_t nd = (size_t)N_NODES * D;   // 6.4M elements
    short* kb = (short*)d_ws;
    short* qb = kb + nd;
    short* vb = qb + nd;
    float* h  = (float*)(vb + nd);
    short* wt = (short*)(h + nd);            // 8 * 16384 shorts
    int* counts    = (int*)(wt + 8 * W_FRAG_SHORTS);
    int* off       = counts + N_NODES;       // N_NODES + 1
    int* cursor    = off + N_NODES + 1;
    int* es        = cursor + N_NODES;
    int* chunk_sum = es + N_EDGES;
    int* chunk_off = chunk_sum + NCHUNKS;
    float* out = (float*)d_out;

    const int eb = (N_EDGES + 255) / 256;
    dim3 gemm_grid(NBLK, 4);

    // Weight prep + CSR build (independent of GEMMs)
    make_wt<<<dim3(8, 8), 256, 0, stream>>>(Wk1, Wq1, Wv1, Ws1, Wk2, Wq2, Wv2, Ws2, wt);
    hipMemsetAsync(counts, 0, N_NODES * sizeof(int), stream);
    hist_kernel   <<<eb, 256, 0, stream>>>(tgt, counts);
    chunk_reduce  <<<NCHUNKS, 256, 0, stream>>>(counts, chunk_sum);
    scan_sums     <<<1, 64, 0, stream>>>(chunk_sum, chunk_off, off);
    scan_chunks   <<<NCHUNKS, 256, 0, stream>>>(counts, chunk_off, off, cursor);
    scatter_kernel<<<eb, 256, 0, stream>>>(src, tgt, cursor, es);

    // Layer 1
    gemm_mfma<false><<<gemm_grid, 256, 0, stream>>>(x, wt, b1, kb, qb, vb, h);
    node_agg<<<N_NODES / 4, 256, 0, stream>>>(off, es, kb, qb, vb, h);

    // Layer 2 (relu fused into A staging)
    gemm_mfma<true><<<gemm_grid, 256, 0, stream>>>(h, wt + 4 * W_FRAG_SHORTS, b2,
                                                   kb, qb, vb, out);
    node_agg<<<N_NODES / 4, 256, 0, stream>>>(off, es, kb, qb, vb, out);
}

// Round 4
// 295.138 us; speedup vs baseline: 5.6214x; 1.1758x over previous
//
#include <hip/hip_runtime.h>

#define N_NODES 50000
#define D 128
#define N_EDGES 400000
#define NCHUNKS ((N_NODES + 255) / 256)   // 196
#define NBLK ((N_NODES + 127) / 128)      // 391
#define W_FRAG_SHORTS 16384               // 32 frags * 64 lanes * 8 bf16 per weight matrix

typedef short s8v  __attribute__((ext_vector_type(8)));   // 8 bf16 (4 VGPRs)
typedef float f4v  __attribute__((ext_vector_type(4)));   // MFMA accumulator

// float -> bf16 round-to-nearest-even
__device__ __forceinline__ unsigned short f2bf(float f) {
    unsigned int u = __float_as_uint(f);
    u += 0x7FFFu + ((u >> 16) & 1u);
    return (unsigned short)(u >> 16);
}
__device__ __forceinline__ float bflo(unsigned int u) { return __uint_as_float(u << 16); }
__device__ __forceinline__ float bfhi(unsigned int u) { return __uint_as_float(u & 0xFFFF0000u); }
// sigmoid with raw v_rcp_f32 (1 ulp) instead of IEEE divide sequence
__device__ __forceinline__ float sigm(float x) {
    return __builtin_amdgcn_rcpf(1.f + __expf(-x));
}

// ---------------------------------------------------------------------------
// x fp32 -> bf16 row-major (once per launch; feeds GEMM1's A staging)
// ---------------------------------------------------------------------------
__global__ __launch_bounds__(256)
void cvt_bf16(const float* __restrict__ X, short* __restrict__ Xb)
{
    const size_t i = ((size_t)blockIdx.x * 256 + threadIdx.x) * 8;
    float4 a0 = *(const float4*)(X + i);
    float4 a1 = *(const float4*)(X + i + 4);
    s8v v;
    v[0] = (short)f2bf(a0.x); v[1] = (short)f2bf(a0.y);
    v[2] = (short)f2bf(a0.z); v[3] = (short)f2bf(a0.w);
    v[4] = (short)f2bf(a1.x); v[5] = (short)f2bf(a1.y);
    v[6] = (short)f2bf(a1.z); v[7] = (short)f2bf(a1.w);
    *(s8v*)(Xb + i) = v;
}

// ---------------------------------------------------------------------------
// Weight prep: fp32 W[k][n] -> bf16 B-fragment-major Wt (unchanged from R3).
// ---------------------------------------------------------------------------
__global__ __launch_bounds__(256)
void make_wt(const float* __restrict__ W0, const float* __restrict__ W1,
             const float* __restrict__ W2, const float* __restrict__ W3,
             const float* __restrict__ W4, const float* __restrict__ W5,
             const float* __restrict__ W6, const float* __restrict__ W7,
             short* __restrict__ Wt)
{
    const int wsel = blockIdx.x;
    const float* W = (wsel == 0) ? W0 : (wsel == 1) ? W1 : (wsel == 2) ? W2 :
                     (wsel == 3) ? W3 : (wsel == 4) ? W4 : (wsel == 5) ? W5 :
                     (wsel == 6) ? W6 : W7;
    const int slot = blockIdx.y * 256 + threadIdx.x;
    const int frag = slot >> 6;
    const int lane = slot & 63;
    const int n    = (frag >> 2) * 16 + (lane & 15);
    const int kc   = frag & 3;
    const int quad = lane >> 4;
    const int k0   = kc * 32 + quad * 8;

    s8v v;
#pragma unroll
    for (int j = 0; j < 8; ++j)
        v[j] = (short)f2bf(W[(size_t)(k0 + j) * D + n]);
    *(s8v*)(Wt + (size_t)wsel * W_FRAG_SHORTS + (size_t)slot * 8) = v;
}

// ---------------------------------------------------------------------------
// bf16-MFMA projection GEMM, bf16 A input. 128x128 tile, K=128 staged once
// into fragment-major LDS (XOR swizzle; staging = pure dwordx4->ds_write_b128).
// sel: 0 -> K (bf16), 1 -> Q half of QV, 2 -> V half of QV, 3 -> fp32 Agg+bias.
// ---------------------------------------------------------------------------
__global__ __launch_bounds__(256)
void gemm_mfma(const short* __restrict__ Xb, const short* __restrict__ WtL,
               const float* __restrict__ bias,
               short* __restrict__ Kb, short* __restrict__ QV,
               float* __restrict__ Agg)
{
    __shared__ short As[16384];   // 32 KB

    const int m0  = blockIdx.x * 128;
    const int sel = blockIdx.y;
    const int tid = threadIdx.x;

    // ---- Stage A tile (128 rows x 128 k, bf16) fragment-major ----
#pragma unroll
    for (int i = 0; i < 8; ++i) {
        const int m   = (tid >> 4) + 16 * i;
        const int oct = tid & 15;
        const int row = m0 + m;
        s8v v = (s8v){0, 0, 0, 0, 0, 0, 0, 0};
        if (row < N_NODES)
            v = *(const s8v*)(Xb + (size_t)row * D + oct * 8);
        const int kc   = oct >> 2;
        const int quad = oct & 3;
        const int frag = (m >> 4) * 4 + kc;
        const int slot = ((m & 15) + 16 * quad) ^ (kc << 1);
        *(s8v*)&As[frag * 512 + slot * 8] = v;
    }
    __syncthreads();

    // ---- MFMA main: wave w covers rows 32w..32w+31, all 128 cols ----
    const int lane = tid & 63;
    const int w    = tid >> 6;
    const short* __restrict__ Wf = WtL + (size_t)sel * W_FRAG_SHORTS;

    f4v acc[2][8];
#pragma unroll
    for (int mt = 0; mt < 2; ++mt)
#pragma unroll
        for (int nt = 0; nt < 8; ++nt)
            acc[mt][nt] = (f4v){0.f, 0.f, 0.f, 0.f};

#pragma unroll
    for (int kc = 0; kc < 4; ++kc) {
        const int sl = (lane ^ (kc << 1)) * 8;
        s8v a0 = *(const s8v*)&As[((2 * w + 0) * 4 + kc) * 512 + sl];
        s8v a1 = *(const s8v*)&As[((2 * w + 1) * 4 + kc) * 512 + sl];
#pragma unroll
        for (int nt = 0; nt < 8; ++nt) {
            s8v b = *(const s8v*)(Wf + (size_t)(nt * 4 + kc) * 512 + lane * 8);
            acc[0][nt] = __builtin_amdgcn_mfma_f32_16x16x32_bf16(a0, b, acc[0][nt], 0, 0, 0);
            acc[1][nt] = __builtin_amdgcn_mfma_f32_16x16x32_bf16(a1, b, acc[1][nt], 0, 0, 0);
        }
    }

    // ---- Epilogue: C layout col=lane&15, row=(lane>>4)*4+reg ----
    const int col = lane & 15;
#pragma unroll
    for (int mt = 0; mt < 2; ++mt) {
        const int rbase = m0 + (2 * w + mt) * 16 + (lane >> 4) * 4;
        if (sel == 3) {
#pragma unroll
            for (int nt = 0; nt < 8; ++nt) {
                const float bv = bias[nt * 16 + col];
#pragma unroll
                for (int i = 0; i < 4; ++i) {
                    const int row = rbase + i;
                    if (row < N_NODES)
                        Agg[(size_t)row * D + nt * 16 + col] = acc[mt][nt][i] + bv;
                }
            }
        } else {
            // K -> Kb row (stride 128); Q/V -> interleaved QV row (stride 256)
            short* __restrict__ Outb;
            int stride, coff;
            if (sel == 0)      { Outb = Kb; stride = 128; coff = 0;   }
            else if (sel == 1) { Outb = QV; stride = 256; coff = 0;   }
            else               { Outb = QV; stride = 256; coff = 128; }
#pragma unroll
            for (int nt = 0; nt < 8; ++nt)
#pragma unroll
                for (int i = 0; i < 4; ++i) {
                    const int row = rbase + i;
                    if (row < N_NODES)
                        Outb[(size_t)row * stride + coff + nt * 16 + col] =
                            (short)f2bf(acc[mt][nt][i]);
                }
        }
    }
}

// ---------------------------------------------------------------------------
// CSR build (counting sort by target) — unchanged.
// ---------------------------------------------------------------------------
__global__ __launch_bounds__(256)
void hist_kernel(const int* __restrict__ tgt, int* __restrict__ counts)
{
    int e = blockIdx.x * 256 + threadIdx.x;
    if (e < N_EDGES) atomicAdd(&counts[tgt[e]], 1);
}

__global__ __launch_bounds__(256)
void chunk_reduce(const int* __restrict__ counts, int* __restrict__ chunk_sum)
{
    __shared__ int s[256];
    int i = blockIdx.x * 256 + threadIdx.x;
    s[threadIdx.x] = (i < N_NODES) ? counts[i] : 0;
    __syncthreads();
    for (int d = 128; d > 0; d >>= 1) {
        if (threadIdx.x < d) s[threadIdx.x] += s[threadIdx.x + d];
        __syncthreads();
    }
    if (threadIdx.x == 0) chunk_sum[blockIdx.x] = s[0];
}

__global__ void scan_sums(const int* __restrict__ chunk_sum,
                          int* __restrict__ chunk_off, int* __restrict__ off)
{
    if (threadIdx.x == 0) {
        int run = 0;
        for (int i = 0; i < NCHUNKS; ++i) { chunk_off[i] = run; run += chunk_sum[i]; }
        off[N_NODES] = run;
    }
}

__global__ __launch_bounds__(256)
void scan_chunks(const int* __restrict__ counts, const int* __restrict__ chunk_off,
                 int* __restrict__ off, int* __restrict__ cursor)
{
    __shared__ int s[256];
    int i = blockIdx.x * 256 + threadIdx.x;
    int v = (i < N_NODES) ? counts[i] : 0;
    s[threadIdx.x] = v;
    __syncthreads();
    for (int d = 1; d < 256; d <<= 1) {
        int t = (threadIdx.x >= d) ? s[threadIdx.x - d] : 0;
        __syncthreads();
        s[threadIdx.x] += t;
        __syncthreads();
    }
    if (i < N_NODES) {
        int excl = s[threadIdx.x] - v + chunk_off[blockIdx.x];
        off[i]    = excl;
        cursor[i] = excl;
    }
}

__global__ __launch_bounds__(256)
void scatter_kernel(const int* __restrict__ src, const int* __restrict__ tgt,
                    int* __restrict__ cursor, int* __restrict__ es)
{
    int e = blockIdx.x * 256 + threadIdx.x;
    if (e < N_EDGES) {
        int pos = atomicAdd(&cursor[tgt[e]], 1);
        es[pos] = src[e];
    }
}

// ---------------------------------------------------------------------------
// Atomic-free per-node aggregation. One wave per target node; lane owns 2 dims
// (one packed uint). QV interleaved: row = 128 uints, q = row[lane],
// v = row[64+lane] (imm offset +256B). All control/addressing forced scalar
// via readfirstlane. FIRST: out = bf16 relu(skip+acc) -> Hb (row-major bf16).
// else: OutF(=d_out) = skip + acc (skip read from same buffer, RMW).
// ---------------------------------------------------------------------------
template<bool FIRST>
__global__ __launch_bounds__(256)
void node_agg(const int* __restrict__ off, const int* __restrict__ es,
              const short* __restrict__ K, const short* __restrict__ QV,
              const float* __restrict__ Skip, float* __restrict__ OutF,
              unsigned int* __restrict__ Hb)
{
    const int lane = threadIdx.x & 63;
    const int t    = __builtin_amdgcn_readfirstlane(blockIdx.x * 4 + (threadIdx.x >> 6));

    const unsigned int* __restrict__ K1  = (const unsigned int*)K;
    const unsigned int* __restrict__ QV1 = (const unsigned int*)QV;

    const unsigned int ku = K1[(size_t)t * 64 + lane];
    const float kx = bflo(ku), ky = bfhi(ku);

    float ax = 0.f, ay = 0.f, bx = 0.f, by = 0.f;
    const int e0 = __builtin_amdgcn_readfirstlane(off[t]);
    const int e1 = __builtin_amdgcn_readfirstlane(off[t + 1]);

    int e = e0;
    for (; e + 2 <= e1; e += 2) {
        const int s0 = __builtin_amdgcn_readfirstlane(es[e]);
        const int s1 = __builtin_amdgcn_readfirstlane(es[e + 1]);
        const unsigned int* r0 = QV1 + (size_t)s0 * 128;
        const unsigned int* r1 = QV1 + (size_t)s1 * 128;
        const unsigned int q0 = r0[lane], v0 = r0[64 + lane];
        const unsigned int q1 = r1[lane], v1 = r1[64 + lane];
        ax += bflo(v0) * sigm(kx + bflo(q0));
        ay += bfhi(v0) * sigm(ky + bfhi(q0));
        bx += bflo(v1) * sigm(kx + bflo(q1));
        by += bfhi(v1) * sigm(ky + bfhi(q1));
    }
    if (e < e1) {
        const int s0 = __builtin_amdgcn_readfirstlane(es[e]);
        const unsigned int* r0 = QV1 + (size_t)s0 * 128;
        const unsigned int q0 = r0[lane], v0 = r0[64 + lane];
        ax += bflo(v0) * sigm(kx + bflo(q0));
        ay += bfhi(v0) * sigm(ky + bfhi(q0));
    }

    const float2 sk = ((const float2*)Skip)[(size_t)t * 64 + lane];
    const float rx = sk.x + ax + bx;
    const float ry = sk.y + ay + by;

    if (FIRST) {
        // relu + pack to bf16 row-major (low short = dim 2*lane)
        const unsigned int lo = f2bf(fmaxf(rx, 0.f));
        const unsigned int hi = f2bf(fmaxf(ry, 0.f));
        Hb[(size_t)t * 64 + lane] = (hi << 16) | lo;
    } else {
        ((float2*)OutF)[(size_t)t * 64 + lane] = make_float2(rx, ry);
    }
}

extern "C" void kernel_launch(void* const* d_in, const int* in_sizes, int n_in,
                              void* d_out, int out_size, void* d_ws, size_t ws_size,
                              hipStream_t stream)
{
    const float* x   = (const float*)d_in[0];
    const int*   ei  = (const int*)d_in[1];
    const float* Wk1 = (const float*)d_in[2];
    const float* Wq1 = (const float*)d_in[3];
    const float* Wv1 = (const float*)d_in[4];
    const float* Ws1 = (const float*)d_in[5];
    const float* b1  = (const float*)d_in[6];
    const float* Wk2 = (const float*)d_in[7];
    const float* Wq2 = (const float*)d_in[8];
    const float* Wv2 = (const float*)d_in[9];
    const float* Ws2 = (const float*)d_in[10];
    const float* b2  = (const float*)d_in[11];

    const int* src = ei;
    const int* tgt = ei + N_EDGES;

    const size_t nd = (size_t)N_NODES * D;   // 6.4M elements
    short* kb  = (short*)d_ws;               // bf16 K            (nd)
    short* qv  = kb + nd;                    // bf16 QV interleaved (2*nd)
    short* xb  = qv + 2 * nd;                // bf16 x            (nd)
    short* hb  = xb + nd;                    // bf16 relu(h)      (nd)
    float* agg1 = (float*)(hb + nd);         // fp32 x@Ws1+b1     (nd)
    short* wt  = (short*)(agg1 + nd);        // 8 * 16384 shorts
    int* counts    = (int*)(wt + 8 * W_FRAG_SHORTS);
    int* off       = counts + N_NODES;
    int* cursor    = off + N_NODES + 1;
    int* es        = cursor + N_NODES;
    int* chunk_sum = es + N_EDGES;
    int* chunk_off = chunk_sum + NCHUNKS;
    float* out = (float*)d_out;

    const int eb = (N_EDGES + 255) / 256;
    dim3 gemm_grid(NBLK, 4);

    // Prep: x->bf16, weight fragments, CSR by target
    cvt_bf16<<<(int)(nd / (256 * 8)), 256, 0, stream>>>(x, xb);
    make_wt<<<dim3(8, 8), 256, 0, stream>>>(Wk1, Wq1, Wv1, Ws1, Wk2, Wq2, Wv2, Ws2, wt);
    hipMemsetAsync(counts, 0, N_NODES * sizeof(int), stream);
    hist_kernel   <<<eb, 256, 0, stream>>>(tgt, counts);
    chunk_reduce  <<<NCHUNKS, 256, 0, stream>>>(counts, chunk_sum);
    scan_sums     <<<1, 64, 0, stream>>>(chunk_sum, chunk_off, off);
    scan_chunks   <<<NCHUNKS, 256, 0, stream>>>(counts, chunk_off, off, cursor);
    scatter_kernel<<<eb, 256, 0, stream>>>(src, tgt, cursor, es);

    // Layer 1: gemm writes kb/qv + agg1; node_agg emits bf16 relu(h)
    gemm_mfma<<<gemm_grid, 256, 0, stream>>>(xb, wt, b1, kb, qv, agg1);
    node_agg<true><<<N_NODES / 4, 256, 0, stream>>>(off, es, kb, qv, agg1, nullptr,
                                                    (unsigned int*)hb);

    // Layer 2: gemm reads bf16 relu(h); agg target is d_out
    gemm_mfma<<<gemm_grid, 256, 0, stream>>>(hb, wt + 4 * W_FRAG_SHORTS, b2,
                                             kb, qv, out);
    node_agg<false><<<N_NODES / 4, 256, 0, stream>>>(off, es, kb, qv, out, out, nullptr);
}

// Round 5
// 275.614 us; speedup vs baseline: 6.0196x; 1.0708x over previous
//
#include <hip/hip_runtime.h>

#define N_NODES 50000
#define D 128
#define N_EDGES 400000
#define NCHUNKS ((N_NODES + 255) / 256)   // 196
#define NBLK64 ((N_NODES + 63) / 64)      // 782
#define W_FRAG_SHORTS 16384               // 32 frags * 64 lanes * 8 bf16 per weight matrix

typedef short s8v  __attribute__((ext_vector_type(8)));   // 8 bf16 (4 VGPRs)
typedef float f4v  __attribute__((ext_vector_type(4)));   // MFMA accumulator

// float -> bf16 round-to-nearest-even
__device__ __forceinline__ unsigned int f2bf(float f) {
    unsigned int u = __float_as_uint(f);
    u += 0x7FFFu + ((u >> 16) & 1u);
    return u >> 16;
}
__device__ __forceinline__ unsigned int packbf(float a, float b) {
    return (f2bf(b) << 16) | f2bf(a);
}
__device__ __forceinline__ float bflo(unsigned int u) { return __uint_as_float(u << 16); }
__device__ __forceinline__ float bfhi(unsigned int u) { return __uint_as_float(u & 0xFFFF0000u); }
__device__ __forceinline__ float sigm(float x) {
    return __builtin_amdgcn_rcpf(1.f + __expf(-x));   // v_rcp_f32, ~1 ulp
}

// ---------------------------------------------------------------------------
// x fp32 -> bf16 row-major (once per launch)
// ---------------------------------------------------------------------------
__global__ __launch_bounds__(256)
void cvt_bf16(const float* __restrict__ X, short* __restrict__ Xb)
{
    const size_t i = ((size_t)blockIdx.x * 256 + threadIdx.x) * 8;
    float4 a0 = *(const float4*)(X + i);
    float4 a1 = *(const float4*)(X + i + 4);
    s8v v;
    v[0] = (short)f2bf(a0.x); v[1] = (short)f2bf(a0.y);
    v[2] = (short)f2bf(a0.z); v[3] = (short)f2bf(a0.w);
    v[4] = (short)f2bf(a1.x); v[5] = (short)f2bf(a1.y);
    v[6] = (short)f2bf(a1.z); v[7] = (short)f2bf(a1.w);
    *(s8v*)(Xb + i) = v;
}

// ---------------------------------------------------------------------------
// Weight prep: fp32 W[k][n] -> bf16 B-fragment-major Wt (frag = n_tile*4+kc,
// lane = (n%16)+16*quad, 8 consecutive k). Linear in (frag,lane) -> the GEMM
// can stage it with global_load_lds (wave-uniform base + lane*16).
// ---------------------------------------------------------------------------
__global__ __launch_bounds__(256)
void make_wt(const float* __restrict__ W0, const float* __restrict__ W1,
             const float* __restrict__ W2, const float* __restrict__ W3,
             const float* __restrict__ W4, const float* __restrict__ W5,
             const float* __restrict__ W6, const float* __restrict__ W7,
             short* __restrict__ Wt)
{
    const int wsel = blockIdx.x;
    const float* W = (wsel == 0) ? W0 : (wsel == 1) ? W1 : (wsel == 2) ? W2 :
                     (wsel == 3) ? W3 : (wsel == 4) ? W4 : (wsel == 5) ? W5 :
                     (wsel == 6) ? W6 : W7;
    const int slot = blockIdx.y * 256 + threadIdx.x;
    const int frag = slot >> 6;
    const int lane = slot & 63;
    const int n    = (frag >> 2) * 16 + (lane & 15);
    const int kc   = frag & 3;
    const int quad = lane >> 4;
    const int k0   = kc * 32 + quad * 8;

    s8v v;
#pragma unroll
    for (int j = 0; j < 8; ++j)
        v[j] = (short)f2bf(W[(size_t)(k0 + j) * D + n]);
    *(s8v*)(Wt + (size_t)wsel * W_FRAG_SHORTS + (size_t)slot * 8) = v;
}

// ---------------------------------------------------------------------------
// Fused 4-projection MFMA GEMM. Block = 64 rows, loops sel=0..3 internally:
//   A (64x128 bf16) staged once, fragment-major, XOR-swizzled.
//   B staged per sel into LDS via global_load_lds width=16 (no VGPR roundtrip).
//   Wave (wr,wc): rows wr*32..+32, cols wc*64..+64. 32 MFMA + 24 ds_read/sel.
//   Epilogue: C -> LDS fp32 (bank-swizzled), read back float4, pack, coalesced
//   stores. sel0 -> K bf16; sel1/2 -> QV pair-interleaved bf16; sel3 -> fp32
//   Agg = X@Ws + bias.
// QV row layout = 128 uints: uint[2d] = q dims(2d,2d+1), uint[2d+1] = v dims.
// ---------------------------------------------------------------------------
__global__ __launch_bounds__(256)
void gemm_all(const short* __restrict__ Xb, const short* __restrict__ WtL,
              const float* __restrict__ bias,
              short* __restrict__ Kb, unsigned int* __restrict__ QV,
              float* __restrict__ Agg)
{
    __shared__ __align__(16) short As[8192];    // 16 frags * 512 shorts = 16 KB
    __shared__ __align__(16) short Bs[16384];   // 32 frags * 512 shorts = 32 KB (reused as Cs fp32)
    __shared__ __align__(16) float biasS[128];

    const int tid  = threadIdx.x;
    const int lane = tid & 63;
    const int w    = tid >> 6;
    const int wr   = w & 1;     // row half
    const int wc   = w >> 1;    // col half
    const int m0   = blockIdx.x * 64;

    if (tid < 128) biasS[tid] = bias[tid];

    // ---- Stage A tile (64 rows x 128 k) fragment-major, swizzled ----
#pragma unroll
    for (int i = 0; i < 4; ++i) {
        const int m   = (tid >> 4) + 16 * i;   // 0..63
        const int oct = tid & 15;
        const int row = m0 + m;
        s8v v = (s8v){0, 0, 0, 0, 0, 0, 0, 0};
        if (row < N_NODES) v = *(const s8v*)(Xb + (size_t)row * D + oct * 8);
        const int kc = oct >> 2, quad = oct & 3;
        const int frag = (m >> 4) * 4 + kc;
        const int slot = ((m & 15) + 16 * quad) ^ (kc << 1);
        *(s8v*)&As[frag * 512 + slot * 8] = v;
    }

    float* Cs = (float*)Bs;

    for (int sel = 0; sel < 4; ++sel) {
        __syncthreads();   // A ready / previous Cs readers done

        // ---- Stage B (32 KB) via async global->LDS, 16B per lane ----
        const short* Wf = WtL + (size_t)sel * W_FRAG_SHORTS;
#pragma unroll
        for (int j = 0; j < 8; ++j) {
            const int chunk = tid + 256 * j;          // 16B chunk index
            __builtin_amdgcn_global_load_lds(
                (const __attribute__((address_space(1))) unsigned int*)(Wf + chunk * 8),
                (__attribute__((address_space(3))) unsigned int*)(&Bs[(chunk & ~63) * 8]),
                16, 0, 0);
        }
        __syncthreads();   // vmcnt drained by barrier semantics

        // ---- MFMA: 2 m-tiles x 4 n-tiles x 4 k-steps ----
        f4v acc[2][4];
#pragma unroll
        for (int mt = 0; mt < 2; ++mt)
#pragma unroll
            for (int nt = 0; nt < 4; ++nt)
                acc[mt][nt] = (f4v){0.f, 0.f, 0.f, 0.f};

#pragma unroll
        for (int kc = 0; kc < 4; ++kc) {
            const int sl = (lane ^ (kc << 1)) * 8;
            s8v a0 = *(const s8v*)&As[((2 * wr + 0) * 4 + kc) * 512 + sl];
            s8v a1 = *(const s8v*)&As[((2 * wr + 1) * 4 + kc) * 512 + sl];
#pragma unroll
            for (int nt = 0; nt < 4; ++nt) {
                s8v b = *(const s8v*)&Bs[((4 * wc + nt) * 4 + kc) * 512 + lane * 8];
                acc[0][nt] = __builtin_amdgcn_mfma_f32_16x16x32_bf16(a0, b, acc[0][nt], 0, 0, 0);
                acc[1][nt] = __builtin_amdgcn_mfma_f32_16x16x32_bf16(a1, b, acc[1][nt], 0, 0, 0);
            }
        }
        __syncthreads();   // all waves done reading Bs

        // ---- C -> LDS fp32, group-index swizzled by (row>>2)&3 (==lane>>4) ----
        // C layout: row = wr*32+mt*16+(lane>>4)*4+i, col = wc*64+nt*16+(lane&15)
#pragma unroll
        for (int mt = 0; mt < 2; ++mt) {
            const int r0 = wr * 32 + mt * 16 + (lane >> 4) * 4;
#pragma unroll
            for (int nt = 0; nt < 4; ++nt) {
                const int col = wc * 64 + nt * 16 + (lane & 15);
                const int g = col >> 2, jj = col & 3;
#pragma unroll
                for (int i = 0; i < 4; ++i) {
                    const int row = r0 + i;
                    const int gs  = g ^ (((row >> 2) & 3) << 2);
                    Cs[row * 128 + gs * 4 + jj] = acc[mt][nt][i];
                }
            }
        }
        __syncthreads();

        // ---- Read back (conflict-free) + coalesced store ----
#pragma unroll
        for (int j = 0; j < 8; ++j) {
            const int c    = tid + 256 * j;    // fp32 16B chunk: row c>>5, col group c&31
            const int row  = c >> 5;
            const int gg   = c & 31;
            const int gs   = gg ^ (((row >> 2) & 3) << 2);
            const f4v vv   = *(const f4v*)&Cs[row * 128 + gs * 4];
            const int grow = m0 + row;
            if (grow >= N_NODES) continue;
            if (sel == 3) {
                const float4 bv = *(const float4*)&biasS[gg * 4];
                float4 o = make_float4(vv[0] + bv.x, vv[1] + bv.y,
                                       vv[2] + bv.z, vv[3] + bv.w);
                *(float4*)&Agg[(size_t)grow * D + gg * 4] = o;
            } else {
                const unsigned int p0 = packbf(vv[0], vv[1]);
                const unsigned int p1 = packbf(vv[2], vv[3]);
                if (sel == 0) {
                    uint2* kp = (uint2*)((unsigned int*)Kb + (size_t)grow * 64 + gg * 2);
                    *kp = make_uint2(p0, p1);
                } else {
                    // q dims(4gg..)->uints 4gg,4gg+2 ; v -> 4gg+1,4gg+3
                    unsigned int* rowp = QV + (size_t)grow * 128 + gg * 4 + (sel == 2 ? 1 : 0);
                    rowp[0] = p0; rowp[2] = p1;
                }
            }
        }
    }
}

// ---------------------------------------------------------------------------
// CSR build (counting sort by target) — unchanged.
// ---------------------------------------------------------------------------
__global__ __launch_bounds__(256)
void hist_kernel(const int* __restrict__ tgt, int* __restrict__ counts)
{
    int e = blockIdx.x * 256 + threadIdx.x;
    if (e < N_EDGES) atomicAdd(&counts[tgt[e]], 1);
}

__global__ __launch_bounds__(256)
void chunk_reduce(const int* __restrict__ counts, int* __restrict__ chunk_sum)
{
    __shared__ int s[256];
    int i = blockIdx.x * 256 + threadIdx.x;
    s[threadIdx.x] = (i < N_NODES) ? counts[i] : 0;
    __syncthreads();
    for (int d = 128; d > 0; d >>= 1) {
        if (threadIdx.x < d) s[threadIdx.x] += s[threadIdx.x + d];
        __syncthreads();
    }
    if (threadIdx.x == 0) chunk_sum[blockIdx.x] = s[0];
}

__global__ void scan_sums(const int* __restrict__ chunk_sum,
                          int* __restrict__ chunk_off, int* __restrict__ off)
{
    if (threadIdx.x == 0) {
        int run = 0;
        for (int i = 0; i < NCHUNKS; ++i) { chunk_off[i] = run; run += chunk_sum[i]; }
        off[N_NODES] = run;
    }
}

__global__ __launch_bounds__(256)
void scan_chunks(const int* __restrict__ counts, const int* __restrict__ chunk_off,
                 int* __restrict__ off, int* __restrict__ cursor)
{
    __shared__ int s[256];
    int i = blockIdx.x * 256 + threadIdx.x;
    int v = (i < N_NODES) ? counts[i] : 0;
    s[threadIdx.x] = v;
    __syncthreads();
    for (int d = 1; d < 256; d <<= 1) {
        int t = (threadIdx.x >= d) ? s[threadIdx.x - d] : 0;
        __syncthreads();
        s[threadIdx.x] += t;
        __syncthreads();
    }
    if (i < N_NODES) {
        int excl = s[threadIdx.x] - v + chunk_off[blockIdx.x];
        off[i]    = excl;
        cursor[i] = excl;
    }
}

__global__ __launch_bounds__(256)
void scatter_kernel(const int* __restrict__ src, const int* __restrict__ tgt,
                    int* __restrict__ cursor, int* __restrict__ es)
{
    int e = blockIdx.x * 256 + threadIdx.x;
    if (e < N_EDGES) {
        int pos = atomicAdd(&cursor[tgt[e]], 1);
        es[pos] = src[e];
    }
}

// ---------------------------------------------------------------------------
// Atomic-free per-node aggregation. One wave per target node; lane owns dims
// (2l,2l+1). QV pair-interleaved -> ONE uint2 (8B) load per edge per lane.
// FIRST: Hb = bf16 relu(skip+acc); else OutF = skip+acc (fp32, RMW on d_out).
// ---------------------------------------------------------------------------
template<bool FIRST>
__global__ __launch_bounds__(256)
void node_agg(const int* __restrict__ off, const int* __restrict__ es,
              const short* __restrict__ K, const unsigned int* __restrict__ QV,
              const float* __restrict__ Skip, float* __restrict__ OutF,
              unsigned int* __restrict__ Hb)
{
    const int lane = threadIdx.x & 63;
    const int t    = __builtin_amdgcn_readfirstlane(blockIdx.x * 4 + (threadIdx.x >> 6));

    const unsigned int ku = ((const unsigned int*)K)[(size_t)t * 64 + lane];
    const float kx = bflo(ku), ky = bfhi(ku);

    float ax = 0.f, ay = 0.f, bx = 0.f, by = 0.f;
    const int e0 = __builtin_amdgcn_readfirstlane(off[t]);
    const int e1 = __builtin_amdgcn_readfirstlane(off[t + 1]);

    int e = e0;
    for (; e + 2 <= e1; e += 2) {
        const int s0 = __builtin_amdgcn_readfirstlane(es[e]);
        const int s1 = __builtin_amdgcn_readfirstlane(es[e + 1]);
        const uint2 qv0 = ((const uint2*)(QV + (size_t)s0 * 128))[lane];
        const uint2 qv1 = ((const uint2*)(QV + (size_t)s1 * 128))[lane];
        ax += bflo(qv0.y) * sigm(kx + bflo(qv0.x));
        ay += bfhi(qv0.y) * sigm(ky + bfhi(qv0.x));
        bx += bflo(qv1.y) * sigm(kx + bflo(qv1.x));
        by += bfhi(qv1.y) * sigm(ky + bfhi(qv1.x));
    }
    if (e < e1) {
        const int s0 = __builtin_amdgcn_readfirstlane(es[e]);
        const uint2 qv0 = ((const uint2*)(QV + (size_t)s0 * 128))[lane];
        ax += bflo(qv0.y) * sigm(kx + bflo(qv0.x));
        ay += bfhi(qv0.y) * sigm(ky + bfhi(qv0.x));
    }

    const float2 sk = ((const float2*)Skip)[(size_t)t * 64 + lane];
    const float rx = sk.x + ax + bx;
    const float ry = sk.y + ay + by;

    if (FIRST) {
        Hb[(size_t)t * 64 + lane] = packbf(fmaxf(rx, 0.f), fmaxf(ry, 0.f));
    } else {
        ((float2*)OutF)[(size_t)t * 64 + lane] = make_float2(rx, ry);
    }
}

extern "C" void kernel_launch(void* const* d_in, const int* in_sizes, int n_in,
                              void* d_out, int out_size, void* d_ws, size_t ws_size,
                              hipStream_t stream)
{
    const float* x   = (const float*)d_in[0];
    const int*   ei  = (const int*)d_in[1];
    const float* Wk1 = (const float*)d_in[2];
    const float* Wq1 = (const float*)d_in[3];
    const float* Wv1 = (const float*)d_in[4];
    const float* Ws1 = (const float*)d_in[5];
    const float* b1  = (const float*)d_in[6];
    const float* Wk2 = (const float*)d_in[7];
    const float* Wq2 = (const float*)d_in[8];
    const float* Wv2 = (const float*)d_in[9];
    const float* Ws2 = (const float*)d_in[10];
    const float* b2  = (const float*)d_in[11];

    const int* src = ei;
    const int* tgt = ei + N_EDGES;

    const size_t nd = (size_t)N_NODES * D;   // 6.4M elements
    short* kb  = (short*)d_ws;               // bf16 K                (nd shorts)
    short* qv  = kb + nd;                    // bf16 QV interleaved   (2*nd shorts)
    short* xb  = qv + 2 * nd;                // bf16 x                (nd)
    short* hb  = xb + nd;                    // bf16 relu(h)          (nd)
    float* agg1 = (float*)(hb + nd);         // fp32 x@Ws1+b1         (nd)
    short* wt  = (short*)(agg1 + nd);        // 8 * 16384 shorts
    int* counts    = (int*)(wt + 8 * W_FRAG_SHORTS);
    int* off       = counts + N_NODES;
    int* cursor    = off + N_NODES + 1;
    int* es        = cursor + N_NODES;
    int* chunk_sum = es + N_EDGES;
    int* chunk_off = chunk_sum + NCHUNKS;
    float* out = (float*)d_out;

    const int eb = (N_EDGES + 255) / 256;

    // Prep: x->bf16, weight fragments, CSR by target
    cvt_bf16<<<(int)(nd / (256 * 8)), 256, 0, stream>>>(x, xb);
    make_wt<<<dim3(8, 8), 256, 0, stream>>>(Wk1, Wq1, Wv1, Ws1, Wk2, Wq2, Wv2, Ws2, wt);
    hipMemsetAsync(counts, 0, N_NODES * sizeof(int), stream);
    hist_kernel   <<<eb, 256, 0, stream>>>(tgt, counts);
    chunk_reduce  <<<NCHUNKS, 256, 0, stream>>>(counts, chunk_sum);
    scan_sums     <<<1, 64, 0, stream>>>(chunk_sum, chunk_off, off);
    scan_chunks   <<<NCHUNKS, 256, 0, stream>>>(counts, chunk_off, off, cursor);
    scatter_kernel<<<eb, 256, 0, stream>>>(src, tgt, cursor, es);

    // Layer 1
    gemm_all<<<NBLK64, 256, 0, stream>>>(xb, wt, b1, kb, (unsigned int*)qv, agg1);
    node_agg<true><<<N_NODES / 4, 256, 0, stream>>>(off, es, kb, (const unsigned int*)qv,
                                                    agg1, nullptr, (unsigned int*)hb);

    // Layer 2
    gemm_all<<<NBLK64, 256, 0, stream>>>(hb, wt + 4 * W_FRAG_SHORTS, b2,
                                         kb, (unsigned int*)qv, out);
    node_agg<false><<<N_NODES / 4, 256, 0, stream>>>(off, es, kb, (const unsigned int*)qv,
                                                     out, out, nullptr);
}

// Round 6
// 268.741 us; speedup vs baseline: 6.1736x; 1.0256x over previous
//
#include <hip/hip_runtime.h>

#define N_NODES 50000
#define D 128
#define N_EDGES 400000
#define NCHUNKS ((N_NODES + 255) / 256)   // 196
#define NBLK64 ((N_NODES + 63) / 64)      // 782
#define W_FRAG_SHORTS 16384               // 32 frags * 64 lanes * 8 bf16 per weight matrix

#define CVT_BLOCKS 3125                   // 6.4M elems / 2048 per block
#define MW_BLOCKS  64                     // 8 weights * 8 slot-blocks
#define HIST_BLOCKS ((N_EDGES + 255) / 256)   // 1563
#define PREP_BLOCKS (CVT_BLOCKS + MW_BLOCKS + HIST_BLOCKS)

typedef short s8v  __attribute__((ext_vector_type(8)));   // 8 bf16 (4 VGPRs)
typedef float f4v  __attribute__((ext_vector_type(4)));   // MFMA accumulator

// float -> bf16 round-to-nearest-even
__device__ __forceinline__ unsigned int f2bf(float f) {
    unsigned int u = __float_as_uint(f);
    u += 0x7FFFu + ((u >> 16) & 1u);
    return u >> 16;
}
__device__ __forceinline__ unsigned int packbf(float a, float b) {
    return (f2bf(b) << 16) | f2bf(a);
}
__device__ __forceinline__ float bflo(unsigned int u) { return __uint_as_float(u << 16); }
__device__ __forceinline__ float bfhi(unsigned int u) { return __uint_as_float(u & 0xFFFF0000u); }
__device__ __forceinline__ float sigm(float x) {
    return __builtin_amdgcn_rcpf(1.f + __expf(-x));   // v_rcp_f32, ~1 ulp
}

// ---------------------------------------------------------------------------
// Fused prep: [0,CVT) x->bf16 | [CVT,CVT+MW) weight frags | rest: tgt histogram.
// Branches are wave-uniform on blockIdx.x.
// ---------------------------------------------------------------------------
__global__ __launch_bounds__(256)
void prep_all(const float* __restrict__ X, short* __restrict__ Xb,
              const float* __restrict__ W0, const float* __restrict__ W1,
              const float* __restrict__ W2, const float* __restrict__ W3,
              const float* __restrict__ W4, const float* __restrict__ W5,
              const float* __restrict__ W6, const float* __restrict__ W7,
              short* __restrict__ Wt,
              const int* __restrict__ tgt, int* __restrict__ counts)
{
    const int b = blockIdx.x;
    if (b < CVT_BLOCKS) {
        const size_t i = ((size_t)b * 256 + threadIdx.x) * 8;
        float4 a0 = *(const float4*)(X + i);
        float4 a1 = *(const float4*)(X + i + 4);
        s8v v;
        v[0] = (short)f2bf(a0.x); v[1] = (short)f2bf(a0.y);
        v[2] = (short)f2bf(a0.z); v[3] = (short)f2bf(a0.w);
        v[4] = (short)f2bf(a1.x); v[5] = (short)f2bf(a1.y);
        v[6] = (short)f2bf(a1.z); v[7] = (short)f2bf(a1.w);
        *(s8v*)(Xb + i) = v;
    } else if (b < CVT_BLOCKS + MW_BLOCKS) {
        const int bb   = b - CVT_BLOCKS;
        const int wsel = bb >> 3;
        const float* W = (wsel == 0) ? W0 : (wsel == 1) ? W1 : (wsel == 2) ? W2 :
                         (wsel == 3) ? W3 : (wsel == 4) ? W4 : (wsel == 5) ? W5 :
                         (wsel == 6) ? W6 : W7;
        const int slot = (bb & 7) * 256 + threadIdx.x;
        const int frag = slot >> 6;
        const int lane = slot & 63;
        const int n    = (frag >> 2) * 16 + (lane & 15);
        const int kc   = frag & 3;
        const int quad = lane >> 4;
        const int k0   = kc * 32 + quad * 8;
        s8v v;
#pragma unroll
        for (int j = 0; j < 8; ++j)
            v[j] = (short)f2bf(W[(size_t)(k0 + j) * D + n]);
        *(s8v*)(Wt + (size_t)wsel * W_FRAG_SHORTS + (size_t)slot * 8) = v;
    } else {
        const int e = (b - CVT_BLOCKS - MW_BLOCKS) * 256 + threadIdx.x;
        if (e < N_EDGES) atomicAdd(&counts[tgt[e]], 1);
    }
}

// ---------------------------------------------------------------------------
// Fused 4-projection MFMA GEMM (structure unchanged from R5).
// ---------------------------------------------------------------------------
__global__ __launch_bounds__(256)
void gemm_all(const short* __restrict__ Xb, const short* __restrict__ WtL,
              const float* __restrict__ bias,
              short* __restrict__ Kb, unsigned int* __restrict__ QV,
              float* __restrict__ Agg)
{
    __shared__ __align__(16) short As[8192];    // 16 KB
    __shared__ __align__(16) short Bs[16384];   // 32 KB (reused as Cs fp32)
    __shared__ __align__(16) float biasS[128];

    const int tid  = threadIdx.x;
    const int lane = tid & 63;
    const int w    = tid >> 6;
    const int wr   = w & 1;
    const int wc   = w >> 1;
    const int m0   = blockIdx.x * 64;

    if (tid < 128) biasS[tid] = bias[tid];

#pragma unroll
    for (int i = 0; i < 4; ++i) {
        const int m   = (tid >> 4) + 16 * i;
        const int oct = tid & 15;
        const int row = m0 + m;
        s8v v = (s8v){0, 0, 0, 0, 0, 0, 0, 0};
        if (row < N_NODES) v = *(const s8v*)(Xb + (size_t)row * D + oct * 8);
        const int kc = oct >> 2, quad = oct & 3;
        const int frag = (m >> 4) * 4 + kc;
        const int slot = ((m & 15) + 16 * quad) ^ (kc << 1);
        *(s8v*)&As[frag * 512 + slot * 8] = v;
    }

    float* Cs = (float*)Bs;

    for (int sel = 0; sel < 4; ++sel) {
        __syncthreads();

        const short* Wf = WtL + (size_t)sel * W_FRAG_SHORTS;
#pragma unroll
        for (int j = 0; j < 8; ++j) {
            const int chunk = tid + 256 * j;
            __builtin_amdgcn_global_load_lds(
                (const __attribute__((address_space(1))) unsigned int*)(Wf + chunk * 8),
                (__attribute__((address_space(3))) unsigned int*)(&Bs[(chunk & ~63) * 8]),
                16, 0, 0);
        }
        __syncthreads();

        f4v acc[2][4];
#pragma unroll
        for (int mt = 0; mt < 2; ++mt)
#pragma unroll
            for (int nt = 0; nt < 4; ++nt)
                acc[mt][nt] = (f4v){0.f, 0.f, 0.f, 0.f};

#pragma unroll
        for (int kc = 0; kc < 4; ++kc) {
            const int sl = (lane ^ (kc << 1)) * 8;
            s8v a0 = *(const s8v*)&As[((2 * wr + 0) * 4 + kc) * 512 + sl];
            s8v a1 = *(const s8v*)&As[((2 * wr + 1) * 4 + kc) * 512 + sl];
#pragma unroll
            for (int nt = 0; nt < 4; ++nt) {
                s8v b = *(const s8v*)&Bs[((4 * wc + nt) * 4 + kc) * 512 + lane * 8];
                acc[0][nt] = __builtin_amdgcn_mfma_f32_16x16x32_bf16(a0, b, acc[0][nt], 0, 0, 0);
                acc[1][nt] = __builtin_amdgcn_mfma_f32_16x16x32_bf16(a1, b, acc[1][nt], 0, 0, 0);
            }
        }
        __syncthreads();

#pragma unroll
        for (int mt = 0; mt < 2; ++mt) {
            const int r0 = wr * 32 + mt * 16 + (lane >> 4) * 4;
#pragma unroll
            for (int nt = 0; nt < 4; ++nt) {
                const int col = wc * 64 + nt * 16 + (lane & 15);
                const int g = col >> 2, jj = col & 3;
#pragma unroll
                for (int i = 0; i < 4; ++i) {
                    const int row = r0 + i;
                    const int gs  = g ^ (((row >> 2) & 3) << 2);
                    Cs[row * 128 + gs * 4 + jj] = acc[mt][nt][i];
                }
            }
        }
        __syncthreads();

#pragma unroll
        for (int j = 0; j < 8; ++j) {
            const int c    = tid + 256 * j;
            const int row  = c >> 5;
            const int gg   = c & 31;
            const int gs   = gg ^ (((row >> 2) & 3) << 2);
            const f4v vv   = *(const f4v*)&Cs[row * 128 + gs * 4];
            const int grow = m0 + row;
            if (grow >= N_NODES) continue;
            if (sel == 3) {
                const float4 bv = *(const float4*)&biasS[gg * 4];
                float4 o = make_float4(vv[0] + bv.x, vv[1] + bv.y,
                                       vv[2] + bv.z, vv[3] + bv.w);
                *(float4*)&Agg[(size_t)grow * D + gg * 4] = o;
            } else {
                const unsigned int p0 = packbf(vv[0], vv[1]);
                const unsigned int p1 = packbf(vv[2], vv[3]);
                if (sel == 0) {
                    uint2* kp = (uint2*)((unsigned int*)Kb + (size_t)grow * 64 + gg * 2);
                    *kp = make_uint2(p0, p1);
                } else {
                    unsigned int* rowp = QV + (size_t)grow * 128 + gg * 4 + (sel == 2 ? 1 : 0);
                    rowp[0] = p0; rowp[2] = p1;
                }
            }
        }
    }
}

// ---------------------------------------------------------------------------
// CSR scan path. chunk_reduce -> parallel scan_sums (1 block) -> scan_chunks.
// ---------------------------------------------------------------------------
__global__ __launch_bounds__(256)
void chunk_reduce(const int* __restrict__ counts, int* __restrict__ chunk_sum)
{
    __shared__ int s[256];
    int i = blockIdx.x * 256 + threadIdx.x;
    s[threadIdx.x] = (i < N_NODES) ? counts[i] : 0;
    __syncthreads();
    for (int d = 128; d > 0; d >>= 1) {
        if (threadIdx.x < d) s[threadIdx.x] += s[threadIdx.x + d];
        __syncthreads();
    }
    if (threadIdx.x == 0) chunk_sum[blockIdx.x] = s[0];
}

__global__ __launch_bounds__(256)
void scan_sums(const int* __restrict__ chunk_sum,
               int* __restrict__ chunk_off, int* __restrict__ off)
{
    __shared__ int s[256];
    const int tid = threadIdx.x;
    const int v = (tid < NCHUNKS) ? chunk_sum[tid] : 0;
    s[tid] = v;
    __syncthreads();
    for (int d = 1; d < 256; d <<= 1) {
        int t = (tid >= d) ? s[tid - d] : 0;
        __syncthreads();
        s[tid] += t;
        __syncthreads();
    }
    if (tid < NCHUNKS) chunk_off[tid] = s[tid] - v;   // exclusive
    if (tid == NCHUNKS - 1) off[N_NODES] = s[tid];    // total == N_EDGES
}

__global__ __launch_bounds__(256)
void scan_chunks(const int* __restrict__ counts, const int* __restrict__ chunk_off,
                 int* __restrict__ off, int* __restrict__ cursor)
{
    __shared__ int s[256];
    int i = blockIdx.x * 256 + threadIdx.x;
    int v = (i < N_NODES) ? counts[i] : 0;
    s[threadIdx.x] = v;
    __syncthreads();
    for (int d = 1; d < 256; d <<= 1) {
        int t = (threadIdx.x >= d) ? s[threadIdx.x - d] : 0;
        __syncthreads();
        s[threadIdx.x] += t;
        __syncthreads();
    }
    if (i < N_NODES) {
        int excl = s[threadIdx.x] - v + chunk_off[blockIdx.x];
        off[i]    = excl;
        cursor[i] = excl;
    }
}

__global__ __launch_bounds__(256)
void scatter_kernel(const int* __restrict__ src, const int* __restrict__ tgt,
                    int* __restrict__ cursor, int* __restrict__ es)
{
    int e = blockIdx.x * 256 + threadIdx.x;
    if (e < N_EDGES) {
        int pos = atomicAdd(&cursor[tgt[e]], 1);
        es[pos] = src[e];
    }
}

// ---------------------------------------------------------------------------
// Atomic-free per-node aggregation; 4 edges/iter in flight (MLP), one uint2
// gather per edge per lane. Skip row loaded before the loop.
// ---------------------------------------------------------------------------
template<bool FIRST>
__global__ __launch_bounds__(256)
void node_agg(const int* __restrict__ off, const int* __restrict__ es,
              const short* __restrict__ K, const unsigned int* __restrict__ QV,
              const float* __restrict__ Skip, float* __restrict__ OutF,
              unsigned int* __restrict__ Hb)
{
    const int lane = threadIdx.x & 63;
    const int t    = __builtin_amdgcn_readfirstlane(blockIdx.x * 4 + (threadIdx.x >> 6));

    const unsigned int ku = ((const unsigned int*)K)[(size_t)t * 64 + lane];
    const float kx = bflo(ku), ky = bfhi(ku);
    const float2 sk = ((const float2*)Skip)[(size_t)t * 64 + lane];

    float ax = 0.f, ay = 0.f, bx = 0.f, by = 0.f;
    float cx = 0.f, cy = 0.f, dx = 0.f, dy = 0.f;
    const int e0 = __builtin_amdgcn_readfirstlane(off[t]);
    const int e1 = __builtin_amdgcn_readfirstlane(off[t + 1]);

    int e = e0;
    for (; e + 4 <= e1; e += 4) {
        const int s0 = __builtin_amdgcn_readfirstlane(es[e]);
        const int s1 = __builtin_amdgcn_readfirstlane(es[e + 1]);
        const int s2 = __builtin_amdgcn_readfirstlane(es[e + 2]);
        const int s3 = __builtin_amdgcn_readfirstlane(es[e + 3]);
        const uint2 qv0 = ((const uint2*)(QV + (size_t)s0 * 128))[lane];
        const uint2 qv1 = ((const uint2*)(QV + (size_t)s1 * 128))[lane];
        const uint2 qv2 = ((const uint2*)(QV + (size_t)s2 * 128))[lane];
        const uint2 qv3 = ((const uint2*)(QV + (size_t)s3 * 128))[lane];
        ax += bflo(qv0.y) * sigm(kx + bflo(qv0.x));
        ay += bfhi(qv0.y) * sigm(ky + bfhi(qv0.x));
        bx += bflo(qv1.y) * sigm(kx + bflo(qv1.x));
        by += bfhi(qv1.y) * sigm(ky + bfhi(qv1.x));
        cx += bflo(qv2.y) * sigm(kx + bflo(qv2.x));
        cy += bfhi(qv2.y) * sigm(ky + bfhi(qv2.x));
        dx += bflo(qv3.y) * sigm(kx + bflo(qv3.x));
        dy += bfhi(qv3.y) * sigm(ky + bfhi(qv3.x));
    }
    for (; e < e1; ++e) {
        const int s0 = __builtin_amdgcn_readfirstlane(es[e]);
        const uint2 qv0 = ((const uint2*)(QV + (size_t)s0 * 128))[lane];
        ax += bflo(qv0.y) * sigm(kx + bflo(qv0.x));
        ay += bfhi(qv0.y) * sigm(ky + bfhi(qv0.x));
    }

    const float rx = sk.x + (ax + bx) + (cx + dx);
    const float ry = sk.y + (ay + by) + (cy + dy);

    if (FIRST) {
        Hb[(size_t)t * 64 + lane] = packbf(fmaxf(rx, 0.f), fmaxf(ry, 0.f));
    } else {
        ((float2*)OutF)[(size_t)t * 64 + lane] = make_float2(rx, ry);
    }
}

extern "C" void kernel_launch(void* const* d_in, const int* in_sizes, int n_in,
                              void* d_out, int out_size, void* d_ws, size_t ws_size,
                              hipStream_t stream)
{
    const float* x   = (const float*)d_in[0];
    const int*   ei  = (const int*)d_in[1];
    const float* Wk1 = (const float*)d_in[2];
    const float* Wq1 = (const float*)d_in[3];
    const float* Wv1 = (const float*)d_in[4];
    const float* Ws1 = (const float*)d_in[5];
    const float* b1  = (const float*)d_in[6];
    const float* Wk2 = (const float*)d_in[7];
    const float* Wq2 = (const float*)d_in[8];
    const float* Wv2 = (const float*)d_in[9];
    const float* Ws2 = (const float*)d_in[10];
    const float* b2  = (const float*)d_in[11];

    const int* src = ei;
    const int* tgt = ei + N_EDGES;

    const size_t nd = (size_t)N_NODES * D;   // 6.4M elements
    short* kb  = (short*)d_ws;               // bf16 K                (nd shorts)
    short* qv  = kb + nd;                    // bf16 QV interleaved   (2*nd shorts)
    short* xb  = qv + 2 * nd;                // bf16 x                (nd)
    short* hb  = xb + nd;                    // bf16 relu(h)          (nd)
    float* agg1 = (float*)(hb + nd);         // fp32 x@Ws1+b1         (nd)
    short* wt  = (short*)(agg1 + nd);        // 8 * 16384 shorts
    int* counts    = (int*)(wt + 8 * W_FRAG_SHORTS);
    int* off       = counts + N_NODES;
    int* cursor    = off + N_NODES + 1;
    int* es        = cursor + N_NODES;
    int* chunk_sum = es + N_EDGES;
    int* chunk_off = chunk_sum + NCHUNKS;
    float* out = (float*)d_out;

    // Prep (x->bf16 | weight frags | histogram) after zeroing counts
    hipMemsetAsync(counts, 0, N_NODES * sizeof(int), stream);
    prep_all<<<PREP_BLOCKS, 256, 0, stream>>>(x, xb,
                                              Wk1, Wq1, Wv1, Ws1, Wk2, Wq2, Wv2, Ws2,
                                              wt, tgt, counts);
    chunk_reduce  <<<NCHUNKS, 256, 0, stream>>>(counts, chunk_sum);
    scan_sums     <<<1, 256, 0, stream>>>(chunk_sum, chunk_off, off);
    scan_chunks   <<<NCHUNKS, 256, 0, stream>>>(counts, chunk_off, off, cursor);
    scatter_kernel<<<HIST_BLOCKS, 256, 0, stream>>>(src, tgt, cursor, es);

    // Layer 1
    gemm_all<<<NBLK64, 256, 0, stream>>>(xb, wt, b1, kb, (unsigned int*)qv, agg1);
    node_agg<true><<<N_NODES / 4, 256, 0, stream>>>(off, es, kb, (const unsigned int*)qv,
                                                    agg1, nullptr, (unsigned int*)hb);

    // Layer 2
    gemm_all<<<NBLK64, 256, 0, stream>>>(hb, wt + 4 * W_FRAG_SHORTS, b2,
                                         kb, (unsigned int*)qv, out);
    node_agg<false><<<N_NODES / 4, 256, 0, stream>>>(off, es, kb, (const unsigned int*)qv,
                                                     out, out, nullptr);
}